// Round 6
// baseline (176.116 us; speedup 1.0000x reference)
//
#include <hip/hip_runtime.h>
#include <math.h>

// SSIM loss on 8x8 blockified images (16,3,512,512) fp32.
// Reflect-pad + 11x11 separable Gaussian on an 8x8 block == M = W * S * W^T,
// W = reflect-folded 8x8 Gaussian fold matrix. 5 stats (x,y,x2,y2,xy) per
// block-channel. 8 lanes per block-channel, lane owns one ROW (2x float4
// loads). Two lane-local matvecs with an LDS transpose between them.
// Transpose uses __syncthreads()-separated phases over TWO alternating tile
// sets (5 barriers total) — no reliance on intra-wave DS ordering.
// Reduction: block shuffle-reduce -> fixed-point (2^30) int64 atomicAdd into
// an 8-byte accumulator in d_ws (deterministic, ws-size-proof).

#define NBC     196608     // 16*3*64*64 block-channels
#define NPIX    12582912.0 // total ssim_map elements
#define GRID1   6144       // NBC / 32 groups per 256-thread block
#define PAD     12         // floats per LDS tile row (48B)
#define GSTRIDE 100        // floats per group tile; 400B, 16B-aligned
#define FIXSCALE 1073741824.0f  // 2^30
#define C1      1.0e-4f
#define C2      9.0e-4f

struct WMat { float w[64]; };

__device__ __forceinline__ void matvec8(const float* __restrict__ w,
                                        const float S[8], float O[8]) {
#pragma unroll
    for (int i = 0; i < 8; i++) {
        float a = w[i * 8 + 0] * S[0];
#pragma unroll
        for (int c = 1; c < 8; c++) a = fmaf(w[i * 8 + c], S[c], a);
        O[i] = a;
    }
}

__device__ __forceinline__ void twrite(float* tile, int l, const float A[8]) {
    float4* d = reinterpret_cast<float4*>(tile + l * PAD);
    d[0] = make_float4(A[0], A[1], A[2], A[3]);
    d[1] = make_float4(A[4], A[5], A[6], A[7]);
}

__device__ __forceinline__ void tread(const float* tile, int l, float A[8]) {
#pragma unroll
    for (int c = 0; c < 8; c++) A[c] = tile[c * PAD + l];
}

__global__ __launch_bounds__(256) void ssim_partial(const float* __restrict__ x,
                                                    const float* __restrict__ y,
                                                    unsigned long long* __restrict__ acc64,
                                                    WMat Wm) {
    __shared__ __align__(16) float lds[2 * 32 * GSTRIDE];
    __shared__ float redbuf[4];

    const int tid = threadIdx.x;
    const int l   = tid & 7;                 // owned row of the 8x8 block
    const int grp = tid >> 3;                // group in block [0,32)
    const int bc  = blockIdx.x * 32 + grp;   // block-channel [0, NBC)

    const int wb  = bc & 63;
    const int hb  = (bc >> 6) & 63;
    const int img = bc >> 12;                // b*3 + c in [0,48)

    const int rowbase = (img * 512 + hb * 8 + l) * 512 + wb * 8;

    const float4 x0 = *reinterpret_cast<const float4*>(x + rowbase);
    const float4 x1 = *reinterpret_cast<const float4*>(x + rowbase + 4);
    const float4 y0 = *reinterpret_cast<const float4*>(y + rowbase);
    const float4 y1 = *reinterpret_cast<const float4*>(y + rowbase + 4);

    float X[8] = {x0.x, x0.y, x0.z, x0.w, x1.x, x1.y, x1.z, x1.w};
    float Y[8] = {y0.x, y0.y, y0.z, y0.w, y1.x, y1.y, y1.z, y1.w};

    const float* w = Wm.w;
    float* t0 = &lds[grp * GSTRIDE];
    float* t1 = &lds[32 * GSTRIDE + grp * GSTRIDE];

    float A[8], Ccol[8], T[8];
    float mx[8], my[8], mxx[8], myy[8], mxy[8];

    // phase 0: row-conv of X -> t0
    matvec8(w, X, A);  twrite(t0, l, A);
    __syncthreads();
    // phase 1: col-conv from t0 -> mx ; row-conv of Y -> t1
    tread(t0, l, Ccol); matvec8(w, Ccol, mx);
    matvec8(w, Y, A);  twrite(t1, l, A);
    __syncthreads();
    // phase 2: t1 -> my ; X*X -> t0   (t0 last read in phase 1, pre-barrier)
    tread(t1, l, Ccol); matvec8(w, Ccol, my);
#pragma unroll
    for (int i = 0; i < 8; i++) T[i] = X[i] * X[i];
    matvec8(w, T, A);  twrite(t0, l, A);
    __syncthreads();
    // phase 3: t0 -> mxx ; Y*Y -> t1
    tread(t0, l, Ccol); matvec8(w, Ccol, mxx);
#pragma unroll
    for (int i = 0; i < 8; i++) T[i] = Y[i] * Y[i];
    matvec8(w, T, A);  twrite(t1, l, A);
    __syncthreads();
    // phase 4: t1 -> myy ; X*Y -> t0
    tread(t1, l, Ccol); matvec8(w, Ccol, myy);
#pragma unroll
    for (int i = 0; i < 8; i++) T[i] = X[i] * Y[i];
    matvec8(w, T, A);  twrite(t0, l, A);
    __syncthreads();
    // phase 5: t0 -> mxy
    tread(t0, l, Ccol); matvec8(w, Ccol, mxy);

    float s = 0.f;
#pragma unroll
    for (int p = 0; p < 8; p++) {
        float a = mx[p], b = my[p];
        float sx  = mxx[p] - a * a;
        float sy  = myy[p] - b * b;
        float sxy = mxy[p] - a * b;
        float num = fmaf(2.f, a * b, C1) * fmaf(2.f, sxy, C2);
        float den = (fmaf(a, a, b * b) + C1) * (sx + sy + C2);
        float r = __builtin_amdgcn_rcpf(den);
        r = r * (2.f - den * r);               // Newton -> full fp32
        s = fmaf(num, r, s);
    }

    // 64-lane butterfly, then cross-wave partial, then one atomic per block
#pragma unroll
    for (int off = 32; off > 0; off >>= 1) s += __shfl_xor(s, off, 64);
    if ((tid & 63) == 0) redbuf[tid >> 6] = s;
    __syncthreads();
    if (tid == 0) {
        float bs = (redbuf[0] + redbuf[1]) + (redbuf[2] + redbuf[3]);
        long long fx = llrintf(bs * FIXSCALE);
        atomicAdd(acc64, (unsigned long long)fx);
    }
}

__global__ void zero_acc(unsigned long long* p) { *p = 0ull; }

__global__ void ssim_final(const unsigned long long* __restrict__ acc64,
                           float* __restrict__ out) {
    long long s = (long long)*acc64;
    out[0] = (float)(1.0 - ((double)s / (double)FIXSCALE) / NPIX);
}

static WMat make_w() {
    double g[11]; double s = 0.0;
    for (int k = 0; k < 11; k++) { double d = k - 5.0; g[k] = exp(-d * d / 4.5); s += g[k]; }
    for (int k = 0; k < 11; k++) g[k] /= s;
    WMat W{};
    for (int j = 0; j < 8; j++)
        for (int k = 0; k < 11; k++) {
            int t = j + k - 5;
            int rr = t < 0 ? -t : (t > 7 ? 14 - t : t);
            W.w[j * 8 + rr] += (float)g[k];
        }
    return W;
}

extern "C" void kernel_launch(void* const* d_in, const int* in_sizes, int n_in,
                              void* d_out, int out_size, void* d_ws, size_t ws_size,
                              hipStream_t stream) {
    const float* x = (const float*)d_in[0];
    const float* y = (const float*)d_in[1];
    unsigned long long* acc64 = (unsigned long long*)d_ws;  // 8 bytes used
    WMat W = make_w();
    zero_acc<<<1, 1, 0, stream>>>(acc64);
    ssim_partial<<<GRID1, 256, 0, stream>>>(x, y, acc64, W);
    ssim_final<<<1, 1, 0, stream>>>(acc64, (float*)d_out);
}